// Round 7
// baseline (895.633 us; speedup 1.0000x reference)
//
#include <hip/hip_runtime.h>
#include <hip/hip_bf16.h>

#define S_LEN 1024
#define DK 64
#define NW 8

typedef __attribute__((ext_vector_type(8))) short bf16x8;
typedef __attribute__((ext_vector_type(16))) float f32x16;
typedef __attribute__((ext_vector_type(4))) float f32x4;

__device__ __forceinline__ unsigned short f2bf(float f) {
    __hip_bfloat16 h = __float2bfloat16(f);
    unsigned short u; __builtin_memcpy(&u, &h, 2);
    return u;
}
__device__ __forceinline__ bf16x8 load_cvt8(const float* p, float scale) {
    float4 a = *(const float4*)p;
    float4 b = *(const float4*)(p + 4);
    bf16x8 r;
    r[0] = (short)f2bf(a.x * scale); r[1] = (short)f2bf(a.y * scale);
    r[2] = (short)f2bf(a.z * scale); r[3] = (short)f2bf(a.w * scale);
    r[4] = (short)f2bf(b.x * scale); r[5] = (short)f2bf(b.y * scale);
    r[6] = (short)f2bf(b.z * scale); r[7] = (short)f2bf(b.w * scale);
    return r;
}

__global__ __launch_bounds__(512, 6)
void sdpa_kernel(const float* __restrict__ Q, const float* __restrict__ K,
                 const float* __restrict__ V, const int* __restrict__ M,
                 float* __restrict__ OC, float* __restrict__ OA)
{
    __shared__ unsigned long long mlds[32 * 17];        // 4.25 KB mask bits
    __shared__ unsigned short    plds[NW * 32 * 64];    // 32 KB P half-stash (bf16)
    __shared__ float             cbuf[32 * DK];         // 8 KB ctx accumulator
    __shared__ float             wsum[32];              // row-sum accumulator

    const int bid  = blockIdx.x;
    const int lin  = (bid & 7) * 256 + (bid >> 3);      // XCD swizzle
    const int head = lin >> 5;
    const int q0   = (lin & 31) * 32;

    const int tid  = threadIdx.x;
    const int wv   = tid >> 6;
    const int lane = tid & 63;
    const int lo   = tid & 31;
    const int hi   = (tid >> 5) & 1;

    // zero accumulators (ordered before use by barrier #1)
    *(float4*)(cbuf + tid * 4) = float4{0.f, 0.f, 0.f, 0.f};
    if (tid < 32) wsum[tid] = 0.f;

    // ---- Q fragments (A operand): row=lane&31=q, contraction d = s*16 + 8*hi + j
    const float* qptr = Q + (size_t)(head * S_LEN + q0 + lo) * DK + hi * 8;
    bf16x8 qf[4];
#pragma unroll
    for (int s = 0; s < 4; ++s) qf[s] = load_cvt8(qptr + s * 16, 0.125f);

    // ---- Phase 0: ballot-pack this wave's 4 mask rows into LDS bits
    {
        const int* mb = M + (size_t)(head * S_LEN + q0 + wv * 4) * S_LEN;
#pragma unroll
        for (int r4 = 0; r4 < 4; ++r4) {
            int mv[16];
#pragma unroll
            for (int s = 0; s < 16; ++s)
                mv[s] = __builtin_nontemporal_load(mb + r4 * S_LEN + s * 64 + lane);
            unsigned long long bal[16];
#pragma unroll
            for (int s = 0; s < 16; ++s) bal[s] = __ballot(mv[s] != 0);
            if (lane == 0) {
#pragma unroll
                for (int s = 0; s < 16; ++s) mlds[(wv * 4 + r4) * 17 + s] = bal[s];
            }
        }
    }

    // ---- QK^T: wave's 32q x 128k slice, 4 tiles x 4 K-steps
    f32x16 acc[4];
    const float* kbase = K + (size_t)head * S_LEN * DK;
#pragma unroll
    for (int t = 0; t < 4; ++t) {
        const float* kptr = kbase + (size_t)(wv * 128 + t * 32 + lo) * DK + hi * 8;
        f32x16 a;
#pragma unroll
        for (int i = 0; i < 16; ++i) a[i] = 0.f;
#pragma unroll
        for (int s = 0; s < 4; ++s) {
            bf16x8 kf = load_cvt8(kptr + s * 16, 1.f);
            a = __builtin_amdgcn_mfma_f32_32x32x16_bf16(qf[s], kf, a, 0, 0, 0);
        }
        acc[t] = a;
    }

    __syncthreads();   // B1: mask LDS + zeroed accumulators visible

    // ---- mask test (broadcast u32 + bit extract) + exp + per-row partial sums
    const unsigned* m32 = (const unsigned*)mlds;        // row stride 34 u32
    float rs[16];
#pragma unroll
    for (int r = 0; r < 16; ++r) rs[r] = 0.f;
#pragma unroll
    for (int t = 0; t < 4; ++t) {
#pragma unroll
        for (int r = 0; r < 16; ++r) {
            const int row = (r & 3) + 8 * (r >> 2) + 4 * hi;
            const unsigned mw = m32[row * 34 + wv * 4 + t];
            const float e = ((mw >> lo) & 1u) ? 0.f : __expf(acc[t][r]);
            acc[t][r] = e;
            rs[r] += e;
        }
    }

    // ---- cross-lane (32) butterfly sum, then one atomic per (wave,row)
#pragma unroll
    for (int r = 0; r < 16; ++r) {
        float v = rs[r];
        v += __shfl_xor(v, 1, 64);
        v += __shfl_xor(v, 2, 64);
        v += __shfl_xor(v, 4, 64);
        v += __shfl_xor(v, 8, 64);
        v += __shfl_xor(v, 16, 64);
        if (lo == 0) atomicAdd(&wsum[(r & 3) + 8 * (r >> 2) + 4 * hi], v);
    }
    __syncthreads();   // B2: row sums final

    // ---- normalize (in-lane rcp) + attn store BURST (r outer, t inner:
    //      512B row-region in 4 consecutive nt stores; NO compute interleave)
    float* arow = OA + (size_t)(head * S_LEN + q0) * S_LEN;
#pragma unroll
    for (int r = 0; r < 16; ++r) {
        const int row = (r & 3) + 8 * (r >> 2) + 4 * hi;
        const float iv = __builtin_amdgcn_rcpf(wsum[row]);
        float* ar = arow + (size_t)row * S_LEN + wv * 128 + lo;
#pragma unroll
        for (int t = 0; t < 4; ++t) {
            const float pn = acc[t][r] * iv;
            acc[t][r] = pn;
            __builtin_nontemporal_store(pn, ar + t * 32);
        }
    }

    // ---- PV in two 64-k halves: wave-local stash (in-order DS) then MFMAs
    unsigned short* Pw = plds + wv * (32 * 64);
    const float* vbase = V + (size_t)head * S_LEN * DK;
    f32x16 pv0, pv1;
#pragma unroll
    for (int i = 0; i < 16; ++i) { pv0[i] = 0.f; pv1[i] = 0.f; }

#pragma unroll
    for (int h = 0; h < 2; ++h) {
        // stash this half's P (rows x 64 cols, 128B rows, XOR-swizzled)
#pragma unroll
        for (int t2 = 0; t2 < 2; ++t2) {
            const int t = h * 2 + t2;
#pragma unroll
            for (int r = 0; r < 16; ++r) {
                const int row = (r & 3) + 8 * (r >> 2) + 4 * hi;
                const int off = (row * 128 + (t2 * 32 + lo) * 2) ^ ((row & 7) << 4);
                *(unsigned short*)((char*)Pw + off) = f2bf(acc[t][r]);
            }
        }
        // PV over this half's 64 k (4 MFMA k-steps)
#pragma unroll
        for (int st2 = 0; st2 < 4; ++st2) {
            const int off = (lo * 128 + st2 * 32 + hi * 16) ^ ((lo & 7) << 4);
            bf16x8 af = *(const bf16x8*)((const char*)Pw + off);
            const float* vp = vbase + (size_t)(wv * 128 + h * 64 + st2 * 16 + hi * 8) * DK;
            bf16x8 v0, v1;
#pragma unroll
            for (int j = 0; j < 8; ++j) {
                v0[j] = (short)f2bf(vp[j * DK + lo]);
                v1[j] = (short)f2bf(vp[j * DK + 32 + lo]);
            }
            pv0 = __builtin_amdgcn_mfma_f32_32x32x16_bf16(af, v0, pv0, 0, 0, 0);
            pv1 = __builtin_amdgcn_mfma_f32_32x32x16_bf16(af, v1, pv1, 0, 0, 0);
        }
    }

    // ---- cross-wave ctx reduce via LDS atomics
#pragma unroll
    for (int r = 0; r < 16; ++r) {
        const int q = (r & 3) + 8 * (r >> 2) + 4 * hi;
        atomicAdd(&cbuf[q * DK + lo], pv0[r]);
        atomicAdd(&cbuf[q * DK + 32 + lo], pv1[r]);
    }
    __syncthreads();   // B3: ctx partials final

    // ---- coalesced context store (nontemporal float4 per thread)
    {
        f32x4 s4 = *(const f32x4*)(cbuf + tid * 4);
        const int row = tid >> 4;
        const int col = (tid * 4) & 63;
        __builtin_nontemporal_store(s4, (f32x4*)(OC + (size_t)(head * S_LEN + q0 + row) * DK + col));
    }
}

extern "C" void kernel_launch(void* const* d_in, const int* in_sizes, int n_in,
                              void* d_out, int out_size, void* d_ws, size_t ws_size,
                              hipStream_t stream) {
    const float* Q = (const float*)d_in[0];
    const float* K = (const float*)d_in[1];
    const float* V = (const float*)d_in[2];
    const int*   M = (const int*)d_in[3];
    float* OC = (float*)d_out;                       // context: 4*16*1024*64
    float* OA = OC + 4 * 16 * 1024 * 64;             // attn:    4*16*1024*1024
    sdpa_kernel<<<dim3(2048), dim3(512), 0, stream>>>(Q, K, V, M, OC, OA);
}

// Round 8
// 313.508 us; speedup vs baseline: 2.8568x; 2.8568x over previous
//
#include <hip/hip_runtime.h>
#include <hip/hip_bf16.h>

#define S_LEN 1024
#define DK 64
#define NW 8

typedef __attribute__((ext_vector_type(8))) short bf16x8;
typedef __attribute__((ext_vector_type(16))) float f32x16;
typedef __attribute__((ext_vector_type(4))) float f32x4;

__device__ __forceinline__ unsigned short f2bf(float f) {
    __hip_bfloat16 h = __float2bfloat16(f);
    unsigned short u; __builtin_memcpy(&u, &h, 2);
    return u;
}
__device__ __forceinline__ bf16x8 load_cvt8(const float* p, float scale) {
    float4 a = *(const float4*)p;
    float4 b = *(const float4*)(p + 4);
    bf16x8 r;
    r[0] = (short)f2bf(a.x * scale); r[1] = (short)f2bf(a.y * scale);
    r[2] = (short)f2bf(a.z * scale); r[3] = (short)f2bf(a.w * scale);
    r[4] = (short)f2bf(b.x * scale); r[5] = (short)f2bf(b.y * scale);
    r[6] = (short)f2bf(b.z * scale); r[7] = (short)f2bf(b.w * scale);
    return r;
}

// ---- Prep: K -> bf16 B-frag order; V -> bf16 transposed A-frag order.
// wsK[head][kblk(0..31)][s(0..3)][lane(0..63)][j(0..7)] = K[head][kblk*32+(l&31)][s*16+8*(l>>5)+j]
// wsV[head][kt(0..63)][dt(0..1)][lane][j]               = V[head][kt*16+8*(l>>5)+j][(l&31)+32*dt]
__global__ __launch_bounds__(256)
void prep_kernel(const float* __restrict__ K, const float* __restrict__ V,
                 unsigned short* __restrict__ wsK, unsigned short* __restrict__ wsV)
{
    const int b = blockIdx.x;
    const int head = b >> 5, kblk = b & 31;
    const int tid = threadIdx.x;
    const int l = tid & 63, c = tid >> 6;        // c = s (K) / slot (V)

    // K part
    {
        const float* src = K + ((size_t)(head * S_LEN) + kblk * 32 + (l & 31)) * DK
                             + c * 16 + (l >> 5) * 8;
        bf16x8 r = load_cvt8(src, 1.f);
        *(bf16x8*)(wsK + (((size_t)(head * 32 + kblk) * 4 + c) * 64 + l) * 8) = r;
    }
    // V part (transpose)
    {
        const int ktl = c & 1, dt = c >> 1;
        const int kt = kblk * 2 + ktl;
        const float* src = V + ((size_t)(head * S_LEN) + kt * 16 + (l >> 5) * 8) * DK
                             + (l & 31) + 32 * dt;
        bf16x8 r;
#pragma unroll
        for (int j = 0; j < 8; ++j) r[j] = (short)f2bf(src[j * DK]);
        *(bf16x8*)(wsV + (((size_t)(head * 64 + kt) * 2 + dt) * 64 + l) * 8) = r;
    }
}

__global__ __launch_bounds__(512, 2)
void sdpa_kernel(const float* __restrict__ Q, const int* __restrict__ M,
                 const unsigned short* __restrict__ wsK,
                 const unsigned short* __restrict__ wsV,
                 float* __restrict__ OC, float* __restrict__ OA)
{
    __shared__ unsigned long long mlds[32 * 17];        // 4.25 KB mask bits
    __shared__ unsigned short    plds[NW * 32 * 64];    // 32 KB P half-stash (bf16)
    __shared__ float             cbuf[32 * DK];         // 8 KB ctx accumulator (xor-swizzled cols)
    __shared__ float             wsum[32];              // row sums

    const int bid  = blockIdx.x;
    const int lin  = (bid & 7) * 256 + (bid >> 3);      // XCD swizzle
    const int head = lin >> 5;
    const int q0   = (lin & 31) * 32;

    const int tid  = threadIdx.x;
    const int wv   = tid >> 6;
    const int lane = tid & 63;
    const int lo   = tid & 31;
    const int hi   = (tid >> 5) & 1;

    *(float4*)(cbuf + tid * 4) = float4{0.f, 0.f, 0.f, 0.f};
    if (tid < 32) wsum[tid] = 0.f;

    // ---- Q fragments (A operand), pre-scaled by 1/8
    const float* qptr = Q + (size_t)(head * S_LEN + q0 + lo) * DK + hi * 8;
    bf16x8 qf[4];
#pragma unroll
    for (int s = 0; s < 4; ++s) qf[s] = load_cvt8(qptr + s * 16, 0.125f);

    // ---- ballot-pack this wave's 4 mask rows into LDS bits
    {
        const int* mb = M + (size_t)(head * S_LEN + q0 + wv * 4) * S_LEN;
#pragma unroll
        for (int r4 = 0; r4 < 4; ++r4) {
            int mv[16];
#pragma unroll
            for (int s = 0; s < 16; ++s)
                mv[s] = __builtin_nontemporal_load(mb + r4 * S_LEN + s * 64 + lane);
            unsigned long long bal[16];
#pragma unroll
            for (int s = 0; s < 16; ++s) bal[s] = __ballot(mv[s] != 0);
            if (lane == 0) {
#pragma unroll
                for (int s = 0; s < 16; ++s) mlds[(wv * 4 + r4) * 17 + s] = bal[s];
            }
        }
    }

    // ---- QK^T: B-frags are single 16B coalesced loads from wsK
    f32x16 acc[4];
#pragma unroll
    for (int t = 0; t < 4; ++t) {
        const unsigned short* kp = wsK + ((size_t)(head * 32 + wv * 4 + t) * 4 * 64 + lane) * 8;
        f32x16 a;
#pragma unroll
        for (int i = 0; i < 16; ++i) a[i] = 0.f;
#pragma unroll
        for (int s = 0; s < 4; ++s) {
            bf16x8 kf = *(const bf16x8*)(kp + (size_t)s * 64 * 8);
            a = __builtin_amdgcn_mfma_f32_32x32x16_bf16(qf[s], kf, a, 0, 0, 0);
        }
        acc[t] = a;
    }

    __syncthreads();   // B1: mask bits + zeroed accumulators visible

    // ---- mask test + exp + per-row partial sums
    const unsigned* m32 = (const unsigned*)mlds;        // row stride 34 u32
    float rs[16];
#pragma unroll
    for (int r = 0; r < 16; ++r) rs[r] = 0.f;
#pragma unroll
    for (int t = 0; t < 4; ++t) {
#pragma unroll
        for (int r = 0; r < 16; ++r) {
            const int row = (r & 3) + 8 * (r >> 2) + 4 * hi;
            const unsigned mw = m32[row * 34 + wv * 4 + t];
            const float e = ((mw >> lo) & 1u) ? 0.f : __expf(acc[t][r]);
            acc[t][r] = e;
            rs[r] += e;
        }
    }

    // ---- cross-lane butterfly sum + one atomic per (wave,row)
#pragma unroll
    for (int r = 0; r < 16; ++r) {
        float v = rs[r];
        v += __shfl_xor(v, 1, 64);
        v += __shfl_xor(v, 2, 64);
        v += __shfl_xor(v, 4, 64);
        v += __shfl_xor(v, 8, 64);
        v += __shfl_xor(v, 16, 64);
        if (lo == 0) atomicAdd(&wsum[(r & 3) + 8 * (r >> 2) + 4 * hi], v);
    }
    __syncthreads();   // B2: row sums final

    // ---- normalize + attn store BURST (row-region in 4 consecutive nt stores)
    float* arow = OA + (size_t)(head * S_LEN + q0) * S_LEN;
#pragma unroll
    for (int r = 0; r < 16; ++r) {
        const int row = (r & 3) + 8 * (r >> 2) + 4 * hi;
        const float iv = __builtin_amdgcn_rcpf(wsum[row]);
        float* ar = arow + (size_t)row * S_LEN + wv * 128 + lo;
#pragma unroll
        for (int t = 0; t < 4; ++t) {
            const float pn = acc[t][r] * iv;
            acc[t][r] = pn;
            __builtin_nontemporal_store(pn, ar + t * 32);
        }
    }

    // ---- PV as O^T = V^T * P^T, two 64-k halves; stash read doubles as B-frag of P^T
    unsigned short* Pw = plds + wv * (32 * 64);
    f32x16 pvT0, pvT1;   // rows = d (0..31 / 32..63), cols = q
#pragma unroll
    for (int i = 0; i < 16; ++i) { pvT0[i] = 0.f; pvT1[i] = 0.f; }

#pragma unroll
    for (int h = 0; h < 2; ++h) {
#pragma unroll
        for (int t2 = 0; t2 < 2; ++t2) {
            const int t = h * 2 + t2;
#pragma unroll
            for (int r = 0; r < 16; ++r) {
                const int row = (r & 3) + 8 * (r >> 2) + 4 * hi;
                const int off = (row * 128 + (t2 * 32 + lo) * 2) ^ ((row & 7) << 4);
                *(unsigned short*)((char*)Pw + off) = f2bf(acc[t][r]);
            }
        }
#pragma unroll
        for (int st2 = 0; st2 < 4; ++st2) {
            const int off = (lo * 128 + st2 * 32 + hi * 16) ^ ((lo & 7) << 4);
            bf16x8 pf = *(const bf16x8*)((const char*)Pw + off);   // B-frag of P^T
            const int kt = wv * 8 + h * 4 + st2;
            const unsigned short* vp = wsV + ((size_t)(head * 64 + kt) * 2 * 64 + lane) * 8;
            bf16x8 vf0 = *(const bf16x8*)(vp);                      // dt=0: d 0..31
            bf16x8 vf1 = *(const bf16x8*)(vp + 64 * 8);             // dt=1: d 32..63
            pvT0 = __builtin_amdgcn_mfma_f32_32x32x16_bf16(vf0, pf, pvT0, 0, 0, 0);
            pvT1 = __builtin_amdgcn_mfma_f32_32x32x16_bf16(vf1, pf, pvT1, 0, 0, 0);
        }
    }

    // ---- cross-wave ctx reduce via LDS atomics (q = lo in lanes, d in regs; xor-swizzled)
#pragma unroll
    for (int r = 0; r < 16; ++r) {
        const int d0 = (r & 3) + 8 * (r >> 2) + 4 * hi;
        atomicAdd(&cbuf[lo * DK + ((d0)      ^ ((lo & 15) << 2))], pvT0[r]);
        atomicAdd(&cbuf[lo * DK + ((d0 + 32) ^ ((lo & 15) << 2))], pvT1[r]);
    }
    __syncthreads();   // B3: ctx partials final

    // ---- context store (de-swizzle, nontemporal float4)
    {
        const int q  = tid >> 4;
        const int d4 = (tid * 4) & 63;
        const int pc = d4 ^ ((q & 15) << 2);
        f32x4 s4 = *(const f32x4*)(cbuf + q * DK + pc);
        __builtin_nontemporal_store(s4, (f32x4*)(OC + (size_t)(head * S_LEN + q0 + q) * DK + d4));
    }
}

extern "C" void kernel_launch(void* const* d_in, const int* in_sizes, int n_in,
                              void* d_out, int out_size, void* d_ws, size_t ws_size,
                              hipStream_t stream) {
    const float* Q = (const float*)d_in[0];
    const float* K = (const float*)d_in[1];
    const float* V = (const float*)d_in[2];
    const int*   M = (const int*)d_in[3];
    float* OC = (float*)d_out;                       // context: 4*16*1024*64
    float* OA = OC + 4 * 16 * 1024 * 64;             // attn:    4*16*1024*1024
    unsigned short* wsK = (unsigned short*)d_ws;     // 8 MB
    unsigned short* wsV = wsK + (size_t)64 * 1024 * 64;   // 8 MB
    prep_kernel<<<dim3(2048), dim3(256), 0, stream>>>(K, V, wsK, wsV);
    sdpa_kernel<<<dim3(2048), dim3(512), 0, stream>>>(Q, M, wsK, wsV, OC, OA);
}

// Round 9
// 312.458 us; speedup vs baseline: 2.8664x; 1.0034x over previous
//
#include <hip/hip_runtime.h>
#include <hip/hip_bf16.h>

#define S_LEN 1024
#define DK 64
#define NW 8

typedef __attribute__((ext_vector_type(8))) short bf16x8;
typedef __attribute__((ext_vector_type(16))) float f32x16;
typedef __attribute__((ext_vector_type(4))) float f32x4;

__device__ __forceinline__ unsigned short f2bf(float f) {
    __hip_bfloat16 h = __float2bfloat16(f);
    unsigned short u; __builtin_memcpy(&u, &h, 2);
    return u;
}
__device__ __forceinline__ bf16x8 load_cvt8(const float* p, float scale) {
    float4 a = *(const float4*)p;
    float4 b = *(const float4*)(p + 4);
    bf16x8 r;
    r[0] = (short)f2bf(a.x * scale); r[1] = (short)f2bf(a.y * scale);
    r[2] = (short)f2bf(a.z * scale); r[3] = (short)f2bf(a.w * scale);
    r[4] = (short)f2bf(b.x * scale); r[5] = (short)f2bf(b.y * scale);
    r[6] = (short)f2bf(b.z * scale); r[7] = (short)f2bf(b.w * scale);
    return r;
}

// ---- Prep: K -> bf16 B-frag order; V -> bf16 B-frag (of P*V) order.
// wsK[head][kblk(0..31)][s(0..3)][lane][j] = K[head][kblk*32+(l&31)][s*16+8*(l>>5)+j]
// wsV[head][kt(0..63)][dt(0..1)][lane][j]  = V[head][kt*16+8*(l>>5)+j][(l&31)+32*dt]
__global__ __launch_bounds__(256)
void prep_kernel(const float* __restrict__ K, const float* __restrict__ V,
                 unsigned short* __restrict__ wsK, unsigned short* __restrict__ wsV)
{
    const int b = blockIdx.x;
    const int head = b >> 5, kblk = b & 31;
    const int tid = threadIdx.x;
    const int l = tid & 63, c = tid >> 6;

    // K part
    {
        const float* src = K + ((size_t)(head * S_LEN) + kblk * 32 + (l & 31)) * DK
                             + c * 16 + (l >> 5) * 8;
        bf16x8 r = load_cvt8(src, 1.f);
        *(bf16x8*)(wsK + (((size_t)(head * 32 + kblk) * 4 + c) * 64 + l) * 8) = r;
    }
    // V part (transpose)
    {
        const int ktl = c & 1, dt = c >> 1;
        const int kt = kblk * 2 + ktl;
        const float* src = V + ((size_t)(head * S_LEN) + kt * 16 + (l >> 5) * 8) * DK
                             + (l & 31) + 32 * dt;
        bf16x8 r;
#pragma unroll
        for (int j = 0; j < 8; ++j) r[j] = (short)f2bf(src[j * DK]);
        *(bf16x8*)(wsV + (((size_t)(head * 64 + kt) * 2 + dt) * 64 + l) * 8) = r;
    }
}

__global__ __launch_bounds__(512, 4)
void sdpa_kernel(const float* __restrict__ Q, const int* __restrict__ M,
                 const unsigned short* __restrict__ wsK,
                 const unsigned short* __restrict__ wsV,
                 float* __restrict__ OC, float* __restrict__ OA)
{
    __shared__ unsigned long long mlds[32 * 17];        // 4.25 KB mask bits
    __shared__ unsigned short    plds[NW * 32 * 128];   // 64 KB full P stash (bf16)
    __shared__ float             cbuf[32 * DK];         // 8 KB ctx accumulator
    __shared__ float             wsum[32];              // row sums

    const int bid  = blockIdx.x;
    const int lin  = (bid & 7) * 256 + (bid >> 3);      // XCD swizzle
    const int head = lin >> 5;
    const int q0   = (lin & 31) * 32;

    const int tid  = threadIdx.x;
    const int wv   = tid >> 6;
    const int lane = tid & 63;
    const int lo   = tid & 31;
    const int hi   = (tid >> 5) & 1;

    *(float4*)(cbuf + tid * 4) = float4{0.f, 0.f, 0.f, 0.f};
    if (tid < 32) wsum[tid] = 0.f;

    // ---- Q fragments (A operand), pre-scaled by 1/8
    const float* qptr = Q + (size_t)(head * S_LEN + q0 + lo) * DK + hi * 8;
    bf16x8 qf[4];
#pragma unroll
    for (int s = 0; s < 4; ++s) qf[s] = load_cvt8(qptr + s * 16, 0.125f);

    // ---- ballot-pack this wave's 4 mask rows into LDS bits
    {
        const int* mb = M + (size_t)(head * S_LEN + q0 + wv * 4) * S_LEN;
#pragma unroll
        for (int r4 = 0; r4 < 4; ++r4) {
            int mv[16];
#pragma unroll
            for (int s = 0; s < 16; ++s)
                mv[s] = __builtin_nontemporal_load(mb + r4 * S_LEN + s * 64 + lane);
            unsigned long long bal[16];
#pragma unroll
            for (int s = 0; s < 16; ++s) bal[s] = __ballot(mv[s] != 0);
            if (lane == 0) {
#pragma unroll
                for (int s = 0; s < 16; ++s) mlds[(wv * 4 + r4) * 17 + s] = bal[s];
            }
        }
    }

    // ---- QK^T: B-frags are single 16B coalesced loads from wsK
    f32x16 acc[4];
#pragma unroll
    for (int t = 0; t < 4; ++t) {
        const unsigned short* kp = wsK + ((size_t)(head * 32 + wv * 4 + t) * 4 * 64 + lane) * 8;
        f32x16 a;
#pragma unroll
        for (int i = 0; i < 16; ++i) a[i] = 0.f;
#pragma unroll
        for (int s = 0; s < 4; ++s) {
            bf16x8 kf = *(const bf16x8*)(kp + (size_t)s * 64 * 8);
            a = __builtin_amdgcn_mfma_f32_32x32x16_bf16(qf[s], kf, a, 0, 0, 0);
        }
        acc[t] = a;
    }

    __syncthreads();   // B1: mask bits + zeroed accumulators visible

    // ---- mask test + exp + per-row partial sums
    const unsigned* m32 = (const unsigned*)mlds;        // row stride 34 u32
    float rs[16];
#pragma unroll
    for (int r = 0; r < 16; ++r) rs[r] = 0.f;
#pragma unroll
    for (int t = 0; t < 4; ++t) {
#pragma unroll
        for (int r = 0; r < 16; ++r) {
            const int row = (r & 3) + 8 * (r >> 2) + 4 * hi;
            const unsigned mw = m32[row * 34 + wv * 4 + t];
            const float e = ((mw >> lo) & 1u) ? 0.f : __expf(acc[t][r]);
            acc[t][r] = e;
            rs[r] += e;
        }
    }

    // ---- cross-lane butterfly sum + one atomic per (wave,row)
#pragma unroll
    for (int r = 0; r < 16; ++r) {
        float v = rs[r];
        v += __shfl_xor(v, 1, 64);
        v += __shfl_xor(v, 2, 64);
        v += __shfl_xor(v, 4, 64);
        v += __shfl_xor(v, 8, 64);
        v += __shfl_xor(v, 16, 64);
        if (lo == 0) atomicAdd(&wsum[(r & 3) + 8 * (r >> 2) + 4 * hi], v);
    }
    __syncthreads();   // B2: row sums final

    // ---- normalize + attn store BURST (512B row-region in 4 consecutive nt
    //      stores, no compute interleave) + bf16 P stash; acc DIES here
    float* arow = OA + (size_t)(head * S_LEN + q0) * S_LEN;
    unsigned short* Pw = plds + wv * (32 * 128);
#pragma unroll
    for (int r = 0; r < 16; ++r) {
        const int row = (r & 3) + 8 * (r >> 2) + 4 * hi;
        const float iv = __builtin_amdgcn_rcpf(wsum[row]);
        float* ar = arow + (size_t)row * S_LEN + wv * 128 + lo;
#pragma unroll
        for (int t = 0; t < 4; ++t) {
            const float pn = acc[t][r] * iv;
            __builtin_nontemporal_store(pn, ar + t * 32);
            const int off = (row * 256 + (t * 32 + lo) * 2) ^ ((row & 15) << 4);
            *(unsigned short*)((char*)Pw + off) = f2bf(pn);
        }
    }

    // ---- PV over this wave's 128-k slice (acc dead; pv born -> 64 AGPR peak)
    f32x16 pv0, pv1;
#pragma unroll
    for (int i = 0; i < 16; ++i) { pv0[i] = 0.f; pv1[i] = 0.f; }
#pragma unroll
    for (int st = 0; st < 8; ++st) {
        const int off = (lo * 256 + st * 32 + hi * 16) ^ ((lo & 15) << 4);
        bf16x8 af = *(const bf16x8*)((const char*)Pw + off);   // A-frag of P
        const int kt = wv * 8 + st;
        const unsigned short* vp = wsV + ((size_t)(head * 64 + kt) * 2 * 64 + lane) * 8;
        bf16x8 vf0 = *(const bf16x8*)(vp);                      // d 0..31
        bf16x8 vf1 = *(const bf16x8*)(vp + 64 * 8);             // d 32..63
        pv0 = __builtin_amdgcn_mfma_f32_32x32x16_bf16(af, vf0, pv0, 0, 0, 0);
        pv1 = __builtin_amdgcn_mfma_f32_32x32x16_bf16(af, vf1, pv1, 0, 0, 0);
    }

    // ---- cross-wave ctx reduce via LDS atomics (conflict-free: lanes span banks)
#pragma unroll
    for (int r = 0; r < 16; ++r) {
        const int q = (r & 3) + 8 * (r >> 2) + 4 * hi;
        atomicAdd(&cbuf[q * DK + lo], pv0[r]);
        atomicAdd(&cbuf[q * DK + 32 + lo], pv1[r]);
    }
    __syncthreads();   // B3: ctx partials final

    // ---- coalesced context store (nontemporal float4 per thread)
    {
        f32x4 s4 = *(const f32x4*)(cbuf + tid * 4);
        const int row = tid >> 4;
        const int col = (tid * 4) & 63;
        __builtin_nontemporal_store(s4, (f32x4*)(OC + (size_t)(head * S_LEN + q0 + row) * DK + col));
    }
}

extern "C" void kernel_launch(void* const* d_in, const int* in_sizes, int n_in,
                              void* d_out, int out_size, void* d_ws, size_t ws_size,
                              hipStream_t stream) {
    const float* Q = (const float*)d_in[0];
    const float* K = (const float*)d_in[1];
    const float* V = (const float*)d_in[2];
    const int*   M = (const int*)d_in[3];
    float* OC = (float*)d_out;                       // context: 4*16*1024*64
    float* OA = OC + 4 * 16 * 1024 * 64;             // attn:    4*16*1024*1024
    unsigned short* wsK = (unsigned short*)d_ws;     // 8 MB
    unsigned short* wsV = wsK + (size_t)64 * 1024 * 64;   // 8 MB
    prep_kernel<<<dim3(2048), dim3(256), 0, stream>>>(K, V, wsK, wsV);
    sdpa_kernel<<<dim3(2048), dim3(512), 0, stream>>>(Q, M, wsK, wsV, OC, OA);
}